// Round 2
// baseline (13561.853 us; speedup 1.0000x reference)
//
#include <hip/hip_runtime.h>
#include <hip/hip_bf16.h>

typedef __attribute__((ext_vector_type(8))) short short8;
typedef __attribute__((ext_vector_type(4))) float floatx4;
typedef unsigned int u32;
typedef unsigned long long u64;

#define Bb 32
#define Ss 2048
#define Ii 256
#define Hh 256

// ws layout: [0, 64KB) tagged h ring u32[2][32][256]; [64KB, 64KB+128MB) gx bf16 fragments
// gx layout: [t][wv(32)][lane(64)][8 x u32], each u32 = packed bf16 pair of gate pre-acts
#define RING_U32 (2 * Bb * Hh)
#define GX_OFF 65536
#define GX_BYTES ((size_t)Ss * 32 * 64 * 32)

__device__ __forceinline__ unsigned short f2bf(float f) {
    unsigned int u = __float_as_uint(f);
    u += 0x7fffu + ((u >> 16) & 1u);   // RNE
    return (unsigned short)(u >> 16);
}
__device__ __forceinline__ float bf2f_lo(u32 w) { return __uint_as_float(w << 16); }
__device__ __forceinline__ float bf2f_hi(u32 w) { return __uint_as_float(w & 0xffff0000u); }

__device__ __forceinline__ float fast_sigmoid(float x) {
    return __builtin_amdgcn_rcpf(1.0f + __expf(-x));
}
__device__ __forceinline__ float fast_tanh(float x) {
    return 1.0f - 2.0f * __builtin_amdgcn_rcpf(__expf(2.0f * x) + 1.0f);
}

// ---------------- Phase 1: gx[t] = x_t @ Wx_all + b_all, stored in consumer fragment order
__global__ __launch_bounds__(256, 2)
void lstm_gx_kernel(const float* __restrict__ x,
                    const float* __restrict__ Wf, const float* __restrict__ bfp,
                    const float* __restrict__ Wi, const float* __restrict__ bip,
                    const float* __restrict__ Wc, const float* __restrict__ bcp,
                    const float* __restrict__ Wo, const float* __restrict__ bop,
                    u32* __restrict__ gx)
{
    const int tid = threadIdx.x, wave = tid >> 6, lane = tid & 63;
    const int ln = lane & 15, lg = lane >> 4;
    const int combo = blockIdx.x & 7;
    const int tbase = (blockIdx.x >> 3) * 8;
    const int wg = ((combo & 1) << 2) + wave;        // 0..7
    const int chalf = (combo >> 1) & 1, mtile = combo >> 2;
    const int j0 = wg * 32 + chalf * 16, r0 = mtile * 16;
    const int wv = wg * 4 + chalf * 2 + mtile;       // matches recurrent kernel's wave id

    const float* Wg[4] = {Wf, Wi, Wc, Wo};
    const float* bg[4] = {bfp, bip, bcp, bop};
    float bias[4];
#pragma unroll
    for (int g = 0; g < 4; ++g) bias[g] = bg[g][j0 + ln];

    // x-part weight fragments: rows 256 + 32ks + 8lg + i
    short8 Bf[4][8];
#pragma unroll
    for (int g = 0; g < 4; ++g)
#pragma unroll
        for (int ks = 0; ks < 8; ++ks) {
            short8 v;
#pragma unroll
            for (int i = 0; i < 8; ++i) {
                int k = 256 + 32 * ks + 8 * lg + i;
                v[i] = (short)f2bf(Wg[g][k * Hh + (j0 + ln)]);
            }
            Bf[g][ks] = v;
        }

    for (int it = 0; it < 8; ++it) {
        int t = tbase + it;
        short8 xf[8];
#pragma unroll
        for (int ks = 0; ks < 8; ++ks) {
            const float* px = x + (r0 + ln) * (Ss * Ii) + t * Ii + 32 * ks + 8 * lg;
            floatx4 a = *(const floatx4*)px;
            floatx4 b = *(const floatx4*)(px + 4);
            short8 v;
#pragma unroll
            for (int q = 0; q < 4; ++q) { v[q] = (short)f2bf(a[q]); v[4 + q] = (short)f2bf(b[q]); }
            xf[ks] = v;
        }
        floatx4 acc[4];
#pragma unroll
        for (int g = 0; g < 4; ++g) acc[g] = (floatx4){0.f, 0.f, 0.f, 0.f};
#pragma unroll
        for (int ks = 0; ks < 8; ++ks)
#pragma unroll
            for (int g = 0; g < 4; ++g)
                acc[g] = __builtin_amdgcn_mfma_f32_16x16x32_bf16(xf[ks], Bf[g][ks], acc[g], 0, 0, 0);

        u32 o[8];
#pragma unroll
        for (int g = 0; g < 4; ++g)
#pragma unroll
            for (int rp = 0; rp < 2; ++rp) {
                float v0 = acc[g][2 * rp] + bias[g];
                float v1 = acc[g][2 * rp + 1] + bias[g];
                o[g * 2 + rp] = (u32)f2bf(v0) | ((u32)f2bf(v1) << 16);
            }
        u32* dst = gx + ((size_t)(t * 32 + wv) * 64 + lane) * 8;
        ((uint4*)dst)[0] = make_uint4(o[0], o[1], o[2], o[3]);
        ((uint4*)dst)[1] = make_uint4(o[4], o[5], o[6], o[7]);
    }
}

// ---------------- Phase 2: persistent recurrent kernel, tagged-ring sync, no barriers
template<bool USE_GX>
__global__ __launch_bounds__(256, 1)
void lstm_rec(const float* __restrict__ x,
              const float* __restrict__ h0,
              const float* __restrict__ c0,
              const float* __restrict__ Wf, const float* __restrict__ bfp,
              const float* __restrict__ Wi, const float* __restrict__ bip,
              const float* __restrict__ Wc, const float* __restrict__ bcp,
              const float* __restrict__ Wo, const float* __restrict__ bop,
              float* __restrict__ out,
              u32* ring, const u32* __restrict__ gx)
{
    const int wg = blockIdx.x;
    const int tid = threadIdx.x;
    const int wave = tid >> 6, lane = tid & 63;
    const int mtile = wave & 1, chalf = wave >> 1;
    const int ln = lane & 15, lg = lane >> 4;
    const int j0 = wg * 32 + chalf * 16;
    const int r0 = mtile * 16;
    const int wv = wg * 4 + wave;
    constexpr int NKS = USE_GX ? 8 : 16;

    const float* Wg[4] = {Wf, Wi, Wc, Wo};
    const float* bg[4] = {bfp, bip, bcp, bop};

    short8 Bfrag[4][NKS];
#pragma unroll
    for (int g = 0; g < 4; ++g)
#pragma unroll
        for (int ks = 0; ks < NKS; ++ks) {
            short8 v;
#pragma unroll
            for (int i = 0; i < 8; ++i) {
                int k = 32 * ks + 8 * lg + i;
                v[i] = (short)f2bf(Wg[g][k * Hh + (j0 + ln)]);
            }
            Bfrag[g][ks] = v;
        }

    float bias[4];
    if constexpr (!USE_GX) {
#pragma unroll
        for (int g = 0; g < 4; ++g) bias[g] = bg[g][j0 + ln];
    }

    float cst[4], hl[4];
#pragma unroll
    for (int r = 0; r < 4; ++r) {
        cst[r] = c0[(r0 + 4 * lg + r) * Hh + (j0 + ln)];
        hl[r] = 0.0f;
    }

    // publish h0 tile, tag 1 (tags are t+1, never 0 -> safe vs zeroed or 0xAA ws)
#pragma unroll
    for (int r = 0; r < 4; ++r) {
        int b = r0 + 4 * lg + r, j = j0 + ln;
        u32 wrd = (1u << 16) | (u32)f2bf(h0[b * Hh + j]);
        __hip_atomic_store(ring + b * 256 + j, wrd, __ATOMIC_RELAXED, __HIP_MEMORY_SCOPE_AGENT);
    }

    uint4 g0, g1;
    if constexpr (USE_GX) {
        const uint4* p = (const uint4*)(gx + ((size_t)(0 * 32 + wv) * 64 + lane) * 8);
        g0 = p[0]; g1 = p[1];
    }

    int outbase[4];
#pragma unroll
    for (int r = 0; r < 4; ++r)
        outbase[r] = (r0 + 4 * lg + r) * (Ss * Hh) + (j0 + ln);
    const int xrowbase = (r0 + ln) * (Ss * Ii);

    for (int t = 0; t < Ss; ++t) {
        short8 xf[8];
        if constexpr (!USE_GX) {
#pragma unroll
            for (int ks = 0; ks < 8; ++ks) {
                const float* px = x + xrowbase + t * Ii + 32 * ks + 8 * lg;
                floatx4 a = *(const floatx4*)px;
                floatx4 b = *(const floatx4*)(px + 4);
                short8 v;
#pragma unroll
                for (int q = 0; q < 4; ++q) { v[q] = (short)f2bf(a[q]); v[4 + q] = (short)f2bf(b[q]); }
                xf[ks] = v;
            }
        }

        // ---- poll tagged ring: one MALL round trip gives data + readiness
        const u32 tagh = (u32)(t + 1) << 16;
        const u64 tagh2 = ((u64)tagh << 32) | tagh;
        u64* rb = (u64*)(ring + (t & 1) * (Bb * Hh) + (r0 + ln) * 256 + 8 * lg);
        u64 w[32];
        u32 bad;
        do {
#pragma unroll
            for (int ks = 0; ks < 8; ++ks)
#pragma unroll
                for (int q = 0; q < 4; ++q)
                    w[ks * 4 + q] = __hip_atomic_load(rb + 16 * ks + q,
                                                      __ATOMIC_RELAXED, __HIP_MEMORY_SCOPE_AGENT);
            u64 b64 = 0;
#pragma unroll
            for (int j = 0; j < 32; ++j)
                b64 |= (w[j] ^ tagh2) & 0xFFFF0000FFFF0000ull;
            bad = (u32)(b64 | (b64 >> 32));
        } while (__any(bad != 0));

        // ---- acc init
        floatx4 acc[4];
        if constexpr (USE_GX) {
            acc[0] = (floatx4){bf2f_lo(g0.x), bf2f_hi(g0.x), bf2f_lo(g0.y), bf2f_hi(g0.y)};
            acc[1] = (floatx4){bf2f_lo(g0.z), bf2f_hi(g0.z), bf2f_lo(g0.w), bf2f_hi(g0.w)};
            acc[2] = (floatx4){bf2f_lo(g1.x), bf2f_hi(g1.x), bf2f_lo(g1.y), bf2f_hi(g1.y)};
            acc[3] = (floatx4){bf2f_lo(g1.z), bf2f_hi(g1.z), bf2f_lo(g1.w), bf2f_hi(g1.w)};
            // prefetch next step's gx now (full step of slack to arrive)
            if (t + 1 < Ss) {
                const uint4* p = (const uint4*)(gx + ((size_t)((t + 1) * 32 + wv) * 64 + lane) * 8);
                g0 = p[0]; g1 = p[1];
            }
        } else {
#pragma unroll
            for (int g = 0; g < 4; ++g) acc[g] = (floatx4){bias[g], bias[g], bias[g], bias[g]};
#pragma unroll
            for (int ks = 0; ks < 8; ++ks)
#pragma unroll
                for (int g = 0; g < 4; ++g)
                    acc[g] = __builtin_amdgcn_mfma_f32_16x16x32_bf16(xf[ks], Bfrag[g][8 + ks], acc[g], 0, 0, 0);
        }

        // ---- h-part MFMAs from tagged words
#pragma unroll
        for (int ks = 0; ks < 8; ++ks) {
            short8 hf;
#pragma unroll
            for (int i = 0; i < 8; ++i) {
                u32 word = (u32)(w[ks * 4 + (i >> 1)] >> ((i & 1) * 32));
                hf[i] = (short)(word & 0xffffu);
            }
#pragma unroll
            for (int g = 0; g < 4; ++g)
                acc[g] = __builtin_amdgcn_mfma_f32_16x16x32_bf16(hf, Bfrag[g][ks], acc[g], 0, 0, 0);
        }

        // ---- gates + state update + publish (tag t+2) — no barrier, no drain
        u32* wslot = ring + ((t + 1) & 1) * (Bb * Hh);
        const u32 ntag = (u32)(t + 2) << 16;
#pragma unroll
        for (int r = 0; r < 4; ++r) {
            float fg = fast_sigmoid(acc[0][r]);
            float ig = fast_sigmoid(acc[1][r]);
            float cd = fast_tanh(acc[2][r]);
            float og = fast_sigmoid(acc[3][r]);
            float c  = cst[r] * fg + ig * cd;
            cst[r] = c;
            float h = og * fast_tanh(c);
            hl[r] = h;
            __hip_atomic_store(wslot + (r0 + 4 * lg + r) * 256 + (j0 + ln),
                               ntag | (u32)f2bf(h),
                               __ATOMIC_RELAXED, __HIP_MEMORY_SCOPE_AGENT);
        }
#pragma unroll
        for (int r = 0; r < 4; ++r)
            out[outbase[r] + t * Hh] = hl[r];
    }

    float* hf_out = out + Bb * Ss * Hh;
    float* cf_out = hf_out + Bb * Hh;
#pragma unroll
    for (int r = 0; r < 4; ++r) {
        int b = r0 + 4 * lg + r, j = j0 + ln;
        hf_out[b * Hh + j] = hl[r];
        cf_out[b * Hh + j] = cst[r];
    }
}

extern "C" void kernel_launch(void* const* d_in, const int* in_sizes, int n_in,
                              void* d_out, int out_size, void* d_ws, size_t ws_size,
                              hipStream_t stream) {
    (void)in_sizes; (void)n_in; (void)out_size;
    const float* x  = (const float*)d_in[0];
    const float* h0 = (const float*)d_in[1];
    const float* c0 = (const float*)d_in[2];
    const float* Wf = (const float*)d_in[3]; const float* bf = (const float*)d_in[4];
    const float* Wi = (const float*)d_in[5]; const float* bi = (const float*)d_in[6];
    const float* Wc = (const float*)d_in[7]; const float* bc = (const float*)d_in[8];
    const float* Wo = (const float*)d_in[9]; const float* bo = (const float*)d_in[10];

    u32* ring = (u32*)d_ws;
    u32* gx   = (u32*)((char*)d_ws + GX_OFF);
    bool use_gx = ws_size >= (size_t)GX_OFF + GX_BYTES;

    if (use_gx) {
        hipLaunchKernelGGL(lstm_gx_kernel, dim3(2048), dim3(256), 0, stream,
                           x, Wf, bf, Wi, bi, Wc, bc, Wo, bo, gx);
        hipLaunchKernelGGL((lstm_rec<true>), dim3(8), dim3(256), 0, stream,
                           x, h0, c0, Wf, bf, Wi, bi, Wc, bc, Wo, bo,
                           (float*)d_out, ring, gx);
    } else {
        hipLaunchKernelGGL((lstm_rec<false>), dim3(8), dim3(256), 0, stream,
                           x, h0, c0, Wf, bf, Wi, bi, Wc, bc, Wo, bo,
                           (float*)d_out, ring, (const u32*)nullptr);
    }
}

// Round 5
// 7365.221 us; speedup vs baseline: 1.8413x; 1.8413x over previous
//
#include <hip/hip_runtime.h>
#include <hip/hip_bf16.h>

typedef __attribute__((ext_vector_type(8))) short short8;
typedef __attribute__((ext_vector_type(4))) float floatx4;
typedef __attribute__((ext_vector_type(4))) unsigned int uintx4;
typedef unsigned int u32;
typedef unsigned long long u64;

#define Bb 32
#define Ss 2048
#define Ii 256
#define Hh 256

// ws layout:
//   [4096, 8192)   sentinel tags: u32, line (slot*2+mt) of 16 words (w = wg*2+chalf)
//   [8192, 40960)  data: u32 data[2][32][128] — packed bf16 pairs of h
//   [65536, ...)   gx: bf16 pre-activation fragments (round-2 layout, proven)
#define TAGS_OFF 4096
#define DATA_OFF 8192
#define GX_OFF   65536

#define RETRY_LATCH (1u << 18)
#define RETRY_DEAD  (1u << 22)

__device__ __forceinline__ unsigned short f2bf(float f) {
    unsigned int u = __float_as_uint(f);
    u += 0x7fffu + ((u >> 16) & 1u);   // RNE
    return (unsigned short)(u >> 16);
}
__device__ __forceinline__ float bf2f_lo(u32 w) { return __uint_as_float(w << 16); }
__device__ __forceinline__ float bf2f_hi(u32 w) { return __uint_as_float(w & 0xffff0000u); }

__device__ __forceinline__ float fast_sigmoid(float x) {
    return __builtin_amdgcn_rcpf(1.0f + __expf(-x));
}
__device__ __forceinline__ float fast_tanh(float x) {
    return 1.0f - 2.0f * __builtin_amdgcn_rcpf(__expf(2.0f * x) + 1.0f);
}

__device__ __forceinline__ void vm_drain() {
    asm volatile("s_waitcnt vmcnt(0)" ::: "memory");
}
// device-coherent batched loads (sc0 sc1 = bypass L1 + XCD L2, served at MALL)
__device__ __forceinline__ void tag_load16(const u32* pt, uintx4& a, uintx4& b, uintx4& c, uintx4& d) {
    asm volatile("global_load_dwordx4 %0, %4, off sc0 sc1\n\t"
                 "global_load_dwordx4 %1, %4, off offset:16 sc0 sc1\n\t"
                 "global_load_dwordx4 %2, %4, off offset:32 sc0 sc1\n\t"
                 "global_load_dwordx4 %3, %4, off offset:48 sc0 sc1\n\t"
                 "s_waitcnt vmcnt(0)"
                 : "=v"(a), "=v"(b), "=v"(c), "=v"(d) : "v"(pt) : "memory");
}
__device__ __forceinline__ void data_load8(const u32* pd, uintx4 v[8]) {
    asm volatile("global_load_dwordx4 %0, %8, off sc0 sc1\n\t"
                 "global_load_dwordx4 %1, %8, off offset:64 sc0 sc1\n\t"
                 "global_load_dwordx4 %2, %8, off offset:128 sc0 sc1\n\t"
                 "global_load_dwordx4 %3, %8, off offset:192 sc0 sc1\n\t"
                 "global_load_dwordx4 %4, %8, off offset:256 sc0 sc1\n\t"
                 "global_load_dwordx4 %5, %8, off offset:320 sc0 sc1\n\t"
                 "global_load_dwordx4 %6, %8, off offset:384 sc0 sc1\n\t"
                 "global_load_dwordx4 %7, %8, off offset:448 sc0 sc1\n\t"
                 "s_waitcnt vmcnt(0)"
                 : "=v"(v[0]), "=v"(v[1]), "=v"(v[2]), "=v"(v[3]),
                   "=v"(v[4]), "=v"(v[5]), "=v"(v[6]), "=v"(v[7])
                 : "v"(pd) : "memory");
}

// ---------------- Phase 1: gx[t] = x_t @ Wx_all + b_all (byte-identical to round 2, proven)
__global__ __launch_bounds__(256, 2)
void lstm_gx_kernel(const float* __restrict__ x,
                    const float* __restrict__ Wf, const float* __restrict__ bfp,
                    const float* __restrict__ Wi, const float* __restrict__ bip,
                    const float* __restrict__ Wc, const float* __restrict__ bcp,
                    const float* __restrict__ Wo, const float* __restrict__ bop,
                    u32* __restrict__ gx)
{
    const int tid = threadIdx.x, wave = tid >> 6, lane = tid & 63;
    const int ln = lane & 15, lg = lane >> 4;
    const int combo = blockIdx.x & 7;
    const int tbase = (blockIdx.x >> 3) * 8;
    const int wg = ((combo & 1) << 2) + wave;
    const int chalf = (combo >> 1) & 1, mtile = combo >> 2;
    const int j0 = wg * 32 + chalf * 16, r0 = mtile * 16;
    const int wv = wg * 4 + chalf * 2 + mtile;

    const float* Wg[4] = {Wf, Wi, Wc, Wo};
    const float* bg[4] = {bfp, bip, bcp, bop};
    float bias[4];
#pragma unroll
    for (int g = 0; g < 4; ++g) bias[g] = bg[g][j0 + ln];

    short8 Bf[4][8];
#pragma unroll
    for (int g = 0; g < 4; ++g)
#pragma unroll
        for (int ks = 0; ks < 8; ++ks) {
            short8 v;
#pragma unroll
            for (int i = 0; i < 8; ++i) {
                int k = 256 + 32 * ks + 8 * lg + i;
                v[i] = (short)f2bf(Wg[g][k * Hh + (j0 + ln)]);
            }
            Bf[g][ks] = v;
        }

    for (int it = 0; it < 8; ++it) {
        int t = tbase + it;
        short8 xf[8];
#pragma unroll
        for (int ks = 0; ks < 8; ++ks) {
            const float* px = x + (r0 + ln) * (Ss * Ii) + t * Ii + 32 * ks + 8 * lg;
            floatx4 a = *(const floatx4*)px;
            floatx4 b = *(const floatx4*)(px + 4);
            short8 v;
#pragma unroll
            for (int q = 0; q < 4; ++q) { v[q] = (short)f2bf(a[q]); v[4 + q] = (short)f2bf(b[q]); }
            xf[ks] = v;
        }
        floatx4 acc[4];
#pragma unroll
        for (int g = 0; g < 4; ++g) acc[g] = (floatx4){0.f, 0.f, 0.f, 0.f};
#pragma unroll
        for (int ks = 0; ks < 8; ++ks)
#pragma unroll
            for (int g = 0; g < 4; ++g)
                acc[g] = __builtin_amdgcn_mfma_f32_16x16x32_bf16(xf[ks], Bf[g][ks], acc[g], 0, 0, 0);

        u32 o[8];
#pragma unroll
        for (int g = 0; g < 4; ++g)
#pragma unroll
            for (int rp = 0; rp < 2; ++rp) {
                float v0 = acc[g][2 * rp] + bias[g];
                float v1 = acc[g][2 * rp + 1] + bias[g];
                o[g * 2 + rp] = (u32)f2bf(v0) | ((u32)f2bf(v1) << 16);
            }
        u32* dst = gx + ((size_t)(t * 32 + wv) * 64 + lane) * 8;
        ((uintx4*)dst)[0] = (uintx4){o[0], o[1], o[2], o[3]};
        ((uintx4*)dst)[1] = (uintx4){o[4], o[5], o[6], o[7]};
    }
}

// ---------------- Phase 2: 8 wgs, barrier-free waves, MALL sentinel ring (single scope)
__global__ __launch_bounds__(256, 1)
void lstm_rec5(const float* __restrict__ h0,
               const float* __restrict__ c0,
               const float* __restrict__ Wf,
               const float* __restrict__ Wi,
               const float* __restrict__ Wc,
               const float* __restrict__ Wo,
               float* __restrict__ out,
               u32* tags, u32* data, const u32* __restrict__ gx)
{
    const int wg = blockIdx.x;
    const int tid = threadIdx.x;
    const int wave = tid >> 6, lane = tid & 63;
    const int mt = wave & 1, chalf = wave >> 1;   // batch-half, col-block
    const int ln = lane & 15, lg = lane >> 4;
    const int j0 = wg * 32 + chalf * 16;
    const int j = j0 + ln;
    const int wv = wg * 4 + chalf * 2 + mt;       // gx fragment slot (matches writer)

    const float* Wg[4] = {Wf, Wi, Wc, Wo};
    short8 Bfrag[4][8];                            // h-part weights, full K=256
#pragma unroll
    for (int g = 0; g < 4; ++g)
#pragma unroll
        for (int ks = 0; ks < 8; ++ks) {
            short8 v;
#pragma unroll
            for (int i = 0; i < 8; ++i) {
                int k = 32 * ks + 8 * lg + i;
                v[i] = (short)f2bf(Wg[g][k * Hh + j]);
            }
            Bfrag[g][ks] = v;
        }

    float cst[4], hl[4];
#pragma unroll
    for (int r = 0; r < 4; ++r) {
        cst[r] = c0[(16 * mt + 4 * lg + r) * Hh + j];
        hl[r] = 0.0f;
    }

    bool use_atomic = false;   // one-way safety latch (fires only if sc0/sc1 loads misbehave)

    // publish h[4] (rows 16mt+4lg+r, col j) into `slot` with sentinel `tag`.
    // Writes use agent-scope atomics — round 2's PROVEN device-visible write path.
    auto publish = [&](int slot, u32 tag, const float h[4]) {
        u32 wrd[4];
#pragma unroll
        for (int r = 0; r < 4; ++r) {
            float partner = __shfl_xor(h[r], 1);
            wrd[r] = (u32)f2bf(h[r]) | ((u32)f2bf(partner) << 16);  // valid on even lanes
        }
        u32* pd = data + slot * 4096 + (16 * mt + 4 * lg) * 128 + (j >> 1);
        if ((ln & 1) == 0) {
#pragma unroll
            for (int r = 0; r < 4; ++r)
                __hip_atomic_store(pd + 128 * r, wrd[r], __ATOMIC_RELAXED, __HIP_MEMORY_SCOPE_AGENT);
        }
        vm_drain();   // release: data stores complete before sentinel
        if (lane == 0)
            __hip_atomic_store(tags + (slot * 2 + mt) * 16 + (wg * 2 + chalf), tag,
                               __ATOMIC_RELAXED, __HIP_MEMORY_SCOPE_AGENT);
    };

    // ---- publish h0 (tag 1) into slot 0
    {
        float hv0[4];
#pragma unroll
        for (int r = 0; r < 4; ++r) hv0[r] = h0[(16 * mt + 4 * lg + r) * Hh + j];
        publish(0, 1u, hv0);
    }

    uintx4 g0, g1;
    {
        const uintx4* p = (const uintx4*)(gx + ((size_t)wv * 64 + lane) * 8);
        g0 = p[0]; g1 = p[1];
    }

    for (int t = 0; t < Ss; ++t) {
        const int slot = t & 1;
        const u32 want = (u32)(t + 1);
        const u32* pt = tags + (slot * 2 + mt) * 16;   // 16 producer sentinels, one 64-B line

        // ---- sentinel poll (1 cache line per retry)
        {
            u32 it = 0;
            for (;;) {
                u32 bad;
                if (!use_atomic) {
                    uintx4 a, b, c, d;
                    tag_load16(pt, a, b, c, d);
                    bad = (a.x ^ want) | (a.y ^ want) | (a.z ^ want) | (a.w ^ want)
                        | (b.x ^ want) | (b.y ^ want) | (b.z ^ want) | (b.w ^ want)
                        | (c.x ^ want) | (c.y ^ want) | (c.z ^ want) | (c.w ^ want)
                        | (d.x ^ want) | (d.y ^ want) | (d.z ^ want) | (d.w ^ want);
                } else {
                    bad = 0;
#pragma unroll
                    for (int i = 0; i < 16; ++i)
                        bad |= __hip_atomic_load(pt + i, __ATOMIC_RELAXED,
                                                 __HIP_MEMORY_SCOPE_AGENT) ^ want;
                }
                if (!__any((int)(bad != 0))) break;
                ++it;
                if (it >= RETRY_LATCH) use_atomic = true;  // proven-coherent fallback
                if (it >= RETRY_DEAD) break;               // terminate, never hang
            }
        }

        // ---- one-shot data read: rows 16mt+ln, packed pairs == A-fragments
        uintx4 dv[8];
        const u32* pd = data + slot * 4096 + (16 * mt + ln) * 128 + 4 * lg;
        if (!use_atomic) {
            data_load8(pd, dv);
        } else {
            const u64* pq = (const u64*)pd;
#pragma unroll
            for (int ks = 0; ks < 8; ++ks) {
                u64 u0 = __hip_atomic_load(pq + 8 * ks,     __ATOMIC_RELAXED, __HIP_MEMORY_SCOPE_AGENT);
                u64 u1 = __hip_atomic_load(pq + 8 * ks + 1, __ATOMIC_RELAXED, __HIP_MEMORY_SCOPE_AGENT);
                dv[ks] = (uintx4){(u32)u0, (u32)(u0 >> 32), (u32)u1, (u32)(u1 >> 32)};
            }
        }

        // ---- acc init from gx + prefetch next step's gx (off critical path)
        floatx4 acc[4];
        acc[0] = (floatx4){bf2f_lo(g0.x), bf2f_hi(g0.x), bf2f_lo(g0.y), bf2f_hi(g0.y)};
        acc[1] = (floatx4){bf2f_lo(g0.z), bf2f_hi(g0.z), bf2f_lo(g0.w), bf2f_hi(g0.w)};
        acc[2] = (floatx4){bf2f_lo(g1.x), bf2f_hi(g1.x), bf2f_lo(g1.y), bf2f_hi(g1.y)};
        acc[3] = (floatx4){bf2f_lo(g1.z), bf2f_hi(g1.z), bf2f_lo(g1.w), bf2f_hi(g1.w)};
        if (t + 1 < Ss) {
            const uintx4* pn = (const uintx4*)(gx + ((size_t)((t + 1) * 32 + wv) * 64 + lane) * 8);
            g0 = pn[0]; g1 = pn[1];
        }

        // ---- h-GEMM: 32 MFMAs (dv bit-casts to A-fragments)
#pragma unroll
        for (int ks = 0; ks < 8; ++ks) {
            union { uintx4 u; short8 s; } cv;
            cv.u = dv[ks];
#pragma unroll
            for (int g = 0; g < 4; ++g)
                acc[g] = __builtin_amdgcn_mfma_f32_16x16x32_bf16(cv.s, Bfrag[g][ks], acc[g], 0, 0, 0);
        }

        // ---- gates + state update
        float hnew[4];
#pragma unroll
        for (int r = 0; r < 4; ++r) {
            float fg = fast_sigmoid(acc[0][r]);
            float ig = fast_sigmoid(acc[1][r]);
            float cd = fast_tanh(acc[2][r]);
            float og = fast_sigmoid(acc[3][r]);
            float c  = cst[r] * fg + ig * cd;
            cst[r] = c;
            hnew[r] = og * fast_tanh(c);
            hl[r] = hnew[r];
        }

        // ---- publish first (unblock peers), then HBM out-stores
        publish((t + 1) & 1, (u32)(t + 2), hnew);
#pragma unroll
        for (int r = 0; r < 4; ++r)
            out[(16 * mt + 4 * lg + r) * (Ss * Hh) + t * Hh + j] = hnew[r];
    }

    float* hfo = out + Bb * Ss * Hh;
    float* cfo = hfo + Bb * Hh;
#pragma unroll
    for (int r = 0; r < 4; ++r) {
        int b = 16 * mt + 4 * lg + r;
        hfo[b * Hh + j] = hl[r];
        cfo[b * Hh + j] = cst[r];
    }
}

extern "C" void kernel_launch(void* const* d_in, const int* in_sizes, int n_in,
                              void* d_out, int out_size, void* d_ws, size_t ws_size,
                              hipStream_t stream) {
    (void)in_sizes; (void)n_in; (void)out_size; (void)ws_size;
    const float* x  = (const float*)d_in[0];
    const float* h0 = (const float*)d_in[1];
    const float* c0 = (const float*)d_in[2];
    const float* Wf = (const float*)d_in[3]; const float* bf = (const float*)d_in[4];
    const float* Wi = (const float*)d_in[5]; const float* bi = (const float*)d_in[6];
    const float* Wc = (const float*)d_in[7]; const float* bc = (const float*)d_in[8];
    const float* Wo = (const float*)d_in[9]; const float* bo = (const float*)d_in[10];

    u32* tags = (u32*)((char*)d_ws + TAGS_OFF);
    u32* data = (u32*)((char*)d_ws + DATA_OFF);
    u32* gx   = (u32*)((char*)d_ws + GX_OFF);

    // No zero-init needed: sentinel protocol is poison-safe (0xAAAAAAAA never equals a tag)

    hipLaunchKernelGGL(lstm_gx_kernel, dim3(2048), dim3(256), 0, stream,
                       x, Wf, bf, Wi, bi, Wc, bc, Wo, bo, gx);
    hipLaunchKernelGGL(lstm_rec5, dim3(8), dim3(256), 0, stream,
                       h0, c0, Wf, Wi, Wc, Wo, (float*)d_out, tags, data, gx);
}